// Round 17
// baseline (547.249 us; speedup 1.0000x reference)
//
// v16: prep kernel pre-converts K/V to bf16 swizzled LDS-image tiles in d_ws;
//      k1/k2 stage via raw uint4 copy (no conversion VALU, half the bytes).
//      f2bf bit-manip restored (cvt_pk asm regressed, T12 lesson). v11 fallback
//      if ws_size too small.
#include <hip/hip_runtime.h>

#define S_LEN 2048
#define D_KD  64
#define NKT   32          // S / 64 k-tiles
#define NBH   64          // B*H
#define KSEG  4           // kernel2: key segments per (bh,qt)

typedef __attribute__((ext_vector_type(8))) short short8;   // 8 bf16 (4 VGPRs)
typedef __attribute__((ext_vector_type(4))) float f32x4;    // MFMA C/D

// ---- bf16 round-to-nearest-even from f32 (compiler-scheduled bit-manip) ----
__device__ __forceinline__ unsigned short f2bf(float f) {
    unsigned u = __builtin_bit_cast(unsigned, f);
    return (unsigned short)((u + 0x7fffu + ((u >> 16) & 1u)) >> 16);
}
__device__ __forceinline__ short8 pack8(float4 a, float4 b) {
    short8 r;
    r[0] = (short)f2bf(a.x); r[1] = (short)f2bf(a.y);
    r[2] = (short)f2bf(a.z); r[3] = (short)f2bf(a.w);
    r[4] = (short)f2bf(b.x); r[5] = (short)f2bf(b.y);
    r[6] = (short)f2bf(b.z); r[7] = (short)f2bf(b.w);
    return r;
}

// Cross-wave LDS-visibility barrier WITHOUT vmcnt drain.
__device__ __forceinline__ void ldsbar() {
    asm volatile("s_waitcnt lgkmcnt(0)" ::: "memory");
    __builtin_amdgcn_s_barrier();
}
// Wave-local LDS ordering only (producer == consumer wave).
__device__ __forceinline__ void ldswait() {
    asm volatile("s_waitcnt lgkmcnt(0)" ::: "memory");
    __builtin_amdgcn_sched_barrier(0);
}

// ---- XOR swizzle for [64][64] bf16 tiles (row stride 128B).
__device__ __forceinline__ unsigned swz(int row, int bytecol) {
    return (unsigned)(row * 128 + bytecol) ^
           (((((unsigned)row & 7u) ^ ((unsigned)row >> 3)) & 7u) << 4);
}

// ---- f32 tile loads + converted writes (prep + fallback) ----
__device__ __forceinline__ void load_rm(const float* __restrict__ g,
                                        float4 r[4], int tid) {
#pragma unroll
    for (int j = 0; j < 4; j++) r[j] = *(const float4*)(g + j * 1024 + tid * 4);
}
__device__ __forceinline__ void write_rm(const float4 r[4],
                                         unsigned char* dst, int tid) {
#pragma unroll
    for (int j = 0; j < 4; j++) {
        int idx = j * 1024 + tid * 4;
        int row = idx >> 6, col = idx & 63;
        ushort4 b = make_ushort4(f2bf(r[j].x), f2bf(r[j].y), f2bf(r[j].z), f2bf(r[j].w));
        *(ushort4*)(dst + swz(row, col * 2)) = b;
    }
}
__device__ __forceinline__ void load_tr(const float* __restrict__ g,
                                        float4 r[4], int tid) {
    const int br = tid >> 4, bc = tid & 15;
    const float* gp = g + (4 * br) * 64 + 4 * bc;
#pragma unroll
    for (int j = 0; j < 4; j++) r[j] = *(const float4*)(gp + j * 64);
}
__device__ __forceinline__ void write_tr(const float4 r[4],
                                         unsigned char* dst, int tid) {
    const int br = tid >> 4, bc = tid & 15;
    ushort4 c;
    c = make_ushort4(f2bf(r[0].x), f2bf(r[1].x), f2bf(r[2].x), f2bf(r[3].x));
    *(ushort4*)(dst + swz(4 * bc + 0, 8 * br)) = c;
    c = make_ushort4(f2bf(r[0].y), f2bf(r[1].y), f2bf(r[2].y), f2bf(r[3].y));
    *(ushort4*)(dst + swz(4 * bc + 1, 8 * br)) = c;
    c = make_ushort4(f2bf(r[0].z), f2bf(r[1].z), f2bf(r[2].z), f2bf(r[3].z));
    *(ushort4*)(dst + swz(4 * bc + 2, 8 * br)) = c;
    c = make_ushort4(f2bf(r[0].w), f2bf(r[1].w), f2bf(r[2].w), f2bf(r[3].w));
    *(ushort4*)(dst + swz(4 * bc + 3, 8 * br)) = c;
}
__device__ __forceinline__ void stage_rm(const float* __restrict__ g,
                                         unsigned char* lds, int tid) {
    float4 r[4];
    load_rm(g, r, tid);
    write_rm(r, lds, tid);
}

// 64x64 QK^T, Q from LDS.
__device__ __forceinline__ void qkt(const unsigned char* Qs, const unsigned char* Ks,
                                    int wv, int lr, int lg, f32x4 acc[4]) {
    short8 a0 = *(const short8*)(Qs + swz(16 * wv + lr, 16 * lg));
    short8 a1 = *(const short8*)(Qs + swz(16 * wv + lr, 16 * lg + 64));
#pragma unroll
    for (int nt = 0; nt < 4; nt++) {
        short8 b0 = *(const short8*)(Ks + swz(16 * nt + lr, 16 * lg));
        short8 b1 = *(const short8*)(Ks + swz(16 * nt + lr, 16 * lg + 64));
        acc[nt] = __builtin_amdgcn_mfma_f32_16x16x32_bf16(a0, b0, acc[nt], 0, 0, 0);
        acc[nt] = __builtin_amdgcn_mfma_f32_16x16x32_bf16(a1, b1, acc[nt], 0, 0, 0);
    }
}
// QK^T with Q in registers.
__device__ __forceinline__ void qkt_r(short8 qa0, short8 qa1, const unsigned char* Ks,
                                      int lr, int lg, f32x4 acc[4]) {
#pragma unroll
    for (int nt = 0; nt < 4; nt++) {
        short8 b0 = *(const short8*)(Ks + swz(16 * nt + lr, 16 * lg));
        short8 b1 = *(const short8*)(Ks + swz(16 * nt + lr, 16 * lg + 64));
        acc[nt] = __builtin_amdgcn_mfma_f32_16x16x32_bf16(qa0, b0, acc[nt], 0, 0, 0);
        acc[nt] = __builtin_amdgcn_mfma_f32_16x16x32_bf16(qa1, b1, acc[nt], 0, 0, 0);
    }
}

// ---------------- prep: K/V -> bf16 swizzled tile images in ws ----------------
__global__ __launch_bounds__(256) void conv_kv(
    const float* __restrict__ K, const float* __restrict__ V,
    unsigned char* __restrict__ wsK, unsigned char* __restrict__ wsV) {
    const int blk = blockIdx.x;                // blk = bh*32 + tile
    const int bh = blk >> 5, t = blk & 31;
    const int tid = threadIdx.x;
    const float* Kg = K + ((size_t)bh * S_LEN + t * 64) * D_KD;
    const float* Vg = V + ((size_t)bh * S_LEN + t * 64) * D_KD;
    float4 r[4];
    load_rm(Kg, r, tid);
    write_rm(r, wsK + (size_t)blk * 8192, tid);
    float4 v[4];
    load_tr(Vg, v, tid);
    write_tr(v, wsV + (size_t)blk * 8192, tid);
}

// ---------------- kernel 1 (pre-image path) ----------------
__global__ __launch_bounds__(256) void attn_ctx_pre(
    const float* __restrict__ Q, const unsigned char* __restrict__ wsK,
    const unsigned char* __restrict__ wsV, const float* __restrict__ M,
    float* __restrict__ out, float* __restrict__ invg) {
    __shared__ unsigned char Ks[8192];
    __shared__ unsigned char Vs[8192];
    __shared__ unsigned char Ps[8192];

    const int tid = threadIdx.x;
    const int wv = tid >> 6, lane = tid & 63, lr = lane & 15, lg = lane >> 4;
    // v11 XCD-aware remap
    const int blk = blockIdx.x;
    const int bh = (blk & 7) * 8 + (blk >> 8);
    const int qt = (blk >> 3) & 31;

    const unsigned char* Kimg = wsK + (size_t)(bh * 32) * 8192;
    const unsigned char* Vimg = wsV + (size_t)(bh * 32) * 8192;
    float* ctxg = out + ((size_t)bh * S_LEN + qt * 64) * D_KD;
    const float* Mg = M + (size_t)(qt * 64) * S_LEN;

    // Q A-fragment in registers (one-time; layout validated in v8/v10)
    short8 qa0, qa1;
    {
        const float* qr = Q + ((size_t)bh * S_LEN + qt * 64 + 16 * wv + lr) * D_KD + 8 * lg;
        qa0 = pack8(*(const float4*)(qr), *(const float4*)(qr + 4));
        qa1 = pack8(*(const float4*)(qr + 32), *(const float4*)(qr + 36));
    }

    f32x4 accc[4] = {};
    float rs[4] = {0.f, 0.f, 0.f, 0.f};

    // prologue prefetch: tile 0 images, raw bytes (32B/thread/matrix)
    uint4 kr0, kr1, vr0, vr1;
    kr0 = *(const uint4*)(Kimg + tid * 16);
    kr1 = *(const uint4*)(Kimg + 4096 + tid * 16);
    vr0 = *(const uint4*)(Vimg + tid * 16);
    vr1 = *(const uint4*)(Vimg + 4096 + tid * 16);

    for (int t = 0; t < NKT; t++) {
        *(uint4*)(Ks + tid * 16) = kr0;
        *(uint4*)(Ks + 4096 + tid * 16) = kr1;
        *(uint4*)(Vs + tid * 16) = vr0;
        *(uint4*)(Vs + 4096 + tid * 16) = vr1;
        ldsbar();                             // staging visible; vm stays in flight

        if (t + 1 < NKT) {
            const unsigned char* kn = Kimg + (size_t)(t + 1) * 8192;
            const unsigned char* vn = Vimg + (size_t)(t + 1) * 8192;
            kr0 = *(const uint4*)(kn + tid * 16);
            kr1 = *(const uint4*)(kn + 4096 + tid * 16);
            vr0 = *(const uint4*)(vn + tid * 16);
            vr1 = *(const uint4*)(vn + 4096 + tid * 16);
        }

        float mreg[4][4];
#pragma unroll
        for (int r = 0; r < 4; r++) {
            const float* mrow = Mg + (size_t)(16 * wv + 4 * lg + r) * S_LEN + t * 64;
#pragma unroll
            for (int nt = 0; nt < 4; nt++) mreg[r][nt] = mrow[16 * nt + lr];
        }

        f32x4 acc[4] = {};
        qkt_r(qa0, qa1, Ks, lr, lg, acc);

#pragma unroll
        for (int r = 0; r < 4; r++) {
            const int row = 16 * wv + 4 * lg + r;
#pragma unroll
            for (int nt = 0; nt < 4; nt++) {
                float e = __expf(acc[nt][r] * 0.125f) * mreg[r][nt];
                rs[r] += e;
                *(unsigned short*)(Ps + swz(row, (16 * nt + lr) * 2)) = f2bf(e);
            }
        }
        ldswait();   // P is wave-private

#pragma unroll
        for (int kt = 0; kt < 2; kt++) {
            short8 pa = *(const short8*)(Ps + swz(16 * wv + lr, 16 * lg + 64 * kt));
#pragma unroll
            for (int nt = 0; nt < 4; nt++) {
                short8 vb = *(const short8*)(Vs + swz(16 * nt + lr, 16 * lg + 64 * kt));
                accc[nt] = __builtin_amdgcn_mfma_f32_16x16x32_bf16(pa, vb, accc[nt], 0, 0, 0);
            }
        }
        ldsbar();                             // all reads done before next overwrite
    }

    float inv[4];
#pragma unroll
    for (int r = 0; r < 4; r++) {
        float v = rs[r];
        v += __shfl_xor(v, 1);
        v += __shfl_xor(v, 2);
        v += __shfl_xor(v, 4);
        v += __shfl_xor(v, 8);
        inv[r] = 1.0f / (v + 1e-8f);
    }

#pragma unroll
    for (int r = 0; r < 4; r++) {
        const int row = 16 * wv + 4 * lg + r;
#pragma unroll
        for (int nt = 0; nt < 4; nt++)
            ctxg[(size_t)row * D_KD + 16 * nt + lr] = accc[nt][r] * inv[r];
    }

    if (lr == 0) {
#pragma unroll
        for (int r = 0; r < 4; r++)
            invg[(size_t)bh * S_LEN + qt * 64 + 16 * wv + 4 * lg + r] = inv[r];
    }
}

// ---------------- kernel 2 (pre-image path) ----------------
__global__ __launch_bounds__(256) void attn_mat_pre(
    const float* __restrict__ Q, const unsigned char* __restrict__ wsK,
    const float* __restrict__ M, const float* __restrict__ invg,
    float* __restrict__ out) {
    __shared__ unsigned char Qs[8192];
    __shared__ unsigned char Ks[8192];

    const int tid = threadIdx.x;
    const int wv = tid >> 6, lane = tid & 63, lr = lane & 15, lg = lane >> 4;
    const int ks = blockIdx.x & (KSEG - 1);
    const int qt = (blockIdx.x >> 2) & 31;
    const int bh = blockIdx.x >> 7;

    const float* Qg = Q + ((size_t)bh * S_LEN + qt * 64) * D_KD;
    const unsigned char* Kimg = wsK + (size_t)(bh * 32 + ks * 8) * 8192;
    const float* Mg = M + (size_t)(qt * 64) * S_LEN;
    float* attng = out + (size_t)NBH * S_LEN * D_KD +
                   (size_t)bh * S_LEN * S_LEN + (size_t)(qt * 64) * S_LEN;

    stage_rm(Qg, Qs, tid);

    float inv[4];
#pragma unroll
    for (int r = 0; r < 4; r++)
        inv[r] = invg[(size_t)bh * S_LEN + qt * 64 + 16 * wv + 4 * lg + r];

    const int nt_kt = S_LEN / (64 * KSEG);   // 8 k-tiles per block

    uint4 kr0 = *(const uint4*)(Kimg + tid * 16);
    uint4 kr1 = *(const uint4*)(Kimg + 4096 + tid * 16);

    for (int kt = 0; kt < nt_kt; kt++) {
        const int key0 = ks * (S_LEN / KSEG) + kt * 64;
        *(uint4*)(Ks + tid * 16) = kr0;
        *(uint4*)(Ks + 4096 + tid * 16) = kr1;
        ldsbar();                            // staging visible; stores keep flying

        if (kt + 1 < nt_kt) {
            const unsigned char* kn = Kimg + (size_t)(kt + 1) * 8192;
            kr0 = *(const uint4*)(kn + tid * 16);
            kr1 = *(const uint4*)(kn + 4096 + tid * 16);
        }

        float mreg[4][4];
#pragma unroll
        for (int r = 0; r < 4; r++) {
            const float* mrow = Mg + (size_t)(16 * wv + 4 * lg + r) * S_LEN + key0;
#pragma unroll
            for (int nt = 0; nt < 4; nt++) mreg[r][nt] = mrow[16 * nt + lr];
        }

        f32x4 acc[4] = {};
        qkt(Qs, Ks, wv, lr, lg, acc);

#pragma unroll
        for (int r = 0; r < 4; r++) {
            const int row = 16 * wv + 4 * lg + r;
            float* arow = attng + (size_t)row * S_LEN + key0;
#pragma unroll
            for (int nt = 0; nt < 4; nt++) {
                float e = __expf(acc[nt][r] * 0.125f) * mreg[r][nt] * inv[r];
                __builtin_nontemporal_store(e, arow + 16 * nt + lr);
            }
        }
        ldsbar();                            // qkt ds_reads done before overwrite
    }
}

// ---------------- fallback: v11 kernels (if ws too small) ----------------
__global__ __launch_bounds__(256) void attn_ctx_v11(
    const float* __restrict__ Q, const float* __restrict__ K,
    const float* __restrict__ V, const float* __restrict__ M,
    float* __restrict__ out, float* __restrict__ invg) {
    __shared__ unsigned char Qs[8192];
    __shared__ unsigned char Ks[8192];
    __shared__ unsigned char Vs[8192];
    __shared__ unsigned char Ps[8192];

    const int tid = threadIdx.x;
    const int wv = tid >> 6, lane = tid & 63, lr = lane & 15, lg = lane >> 4;
    const int blk = blockIdx.x;
    const int bh = (blk & 7) * 8 + (blk >> 8);
    const int qt = (blk >> 3) & 31;

    const float* Qg = Q + ((size_t)bh * S_LEN + qt * 64) * D_KD;
    const float* Kg = K + (size_t)bh * S_LEN * D_KD;
    const float* Vg = V + (size_t)bh * S_LEN * D_KD;
    float* ctxg = out + ((size_t)bh * S_LEN + qt * 64) * D_KD;
    const float* Mg = M + (size_t)(qt * 64) * S_LEN;

    stage_rm(Qg, Qs, tid);
    f32x4 accc[4] = {};
    float rs[4] = {0.f, 0.f, 0.f, 0.f};
    float4 kreg[4], vreg[4];
    load_rm(Kg, kreg, tid);
    load_tr(Vg, vreg, tid);

    for (int t = 0; t < NKT; t++) {
        write_rm(kreg, Ks, tid);
        write_tr(vreg, Vs, tid);
        ldsbar();
        if (t + 1 < NKT) {
            load_rm(Kg + (size_t)(t + 1) * 64 * D_KD, kreg, tid);
            load_tr(Vg + (size_t)(t + 1) * 64 * D_KD, vreg, tid);
        }
        float mreg[4][4];
#pragma unroll
        for (int r = 0; r < 4; r++) {
            const float* mrow = Mg + (size_t)(16 * wv + 4 * lg + r) * S_LEN + t * 64;
#pragma unroll
            for (int nt = 0; nt < 4; nt++) mreg[r][nt] = mrow[16 * nt + lr];
        }
        f32x4 acc[4] = {};
        qkt(Qs, Ks, wv, lr, lg, acc);
#pragma unroll
        for (int r = 0; r < 4; r++) {
            const int row = 16 * wv + 4 * lg + r;
#pragma unroll
            for (int nt = 0; nt < 4; nt++) {
                float e = __expf(acc[nt][r] * 0.125f) * mreg[r][nt];
                rs[r] += e;
                *(unsigned short*)(Ps + swz(row, (16 * nt + lr) * 2)) = f2bf(e);
            }
        }
        ldswait();
#pragma unroll
        for (int kt = 0; kt < 2; kt++) {
            short8 pa = *(const short8*)(Ps + swz(16 * wv + lr, 16 * lg + 64 * kt));
#pragma unroll
            for (int nt = 0; nt < 4; nt++) {
                short8 vb = *(const short8*)(Vs + swz(16 * nt + lr, 16 * lg + 64 * kt));
                accc[nt] = __builtin_amdgcn_mfma_f32_16x16x32_bf16(pa, vb, accc[nt], 0, 0, 0);
            }
        }
        ldsbar();
    }
    float inv[4];
#pragma unroll
    for (int r = 0; r < 4; r++) {
        float v = rs[r];
        v += __shfl_xor(v, 1);
        v += __shfl_xor(v, 2);
        v += __shfl_xor(v, 4);
        v += __shfl_xor(v, 8);
        inv[r] = 1.0f / (v + 1e-8f);
    }
#pragma unroll
    for (int r = 0; r < 4; r++) {
        const int row = 16 * wv + 4 * lg + r;
#pragma unroll
        for (int nt = 0; nt < 4; nt++)
            ctxg[(size_t)row * D_KD + 16 * nt + lr] = accc[nt][r] * inv[r];
    }
    if (lr == 0) {
#pragma unroll
        for (int r = 0; r < 4; r++)
            invg[(size_t)bh * S_LEN + qt * 64 + 16 * wv + 4 * lg + r] = inv[r];
    }
}

__global__ __launch_bounds__(256) void attn_mat_v11(
    const float* __restrict__ Q, const float* __restrict__ K,
    const float* __restrict__ M, const float* __restrict__ invg,
    float* __restrict__ out) {
    __shared__ unsigned char Qs[8192];
    __shared__ unsigned char Ks[8192];

    const int tid = threadIdx.x;
    const int wv = tid >> 6, lane = tid & 63, lr = lane & 15, lg = lane >> 4;
    const int ks = blockIdx.x & (KSEG - 1);
    const int qt = (blockIdx.x >> 2) & 31;
    const int bh = blockIdx.x >> 7;

    const float* Qg = Q + ((size_t)bh * S_LEN + qt * 64) * D_KD;
    const float* Kg = K + (size_t)bh * S_LEN * D_KD;
    const float* Mg = M + (size_t)(qt * 64) * S_LEN;
    float* attng = out + (size_t)NBH * S_LEN * D_KD +
                   (size_t)bh * S_LEN * S_LEN + (size_t)(qt * 64) * S_LEN;

    stage_rm(Qg, Qs, tid);
    float inv[4];
#pragma unroll
    for (int r = 0; r < 4; r++)
        inv[r] = invg[(size_t)bh * S_LEN + qt * 64 + 16 * wv + 4 * lg + r];

    const int nt_kt = S_LEN / (64 * KSEG);
    const float* Kseg = Kg + (size_t)(ks * (S_LEN / KSEG)) * D_KD;
    float4 kreg[4];
    load_rm(Kseg, kreg, tid);

    for (int kt = 0; kt < nt_kt; kt++) {
        const int key0 = ks * (S_LEN / KSEG) + kt * 64;
        write_rm(kreg, Ks, tid);
        ldsbar();
        if (kt + 1 < nt_kt)
            load_rm(Kseg + (size_t)(kt + 1) * 64 * D_KD, kreg, tid);
        float mreg[4][4];
#pragma unroll
        for (int r = 0; r < 4; r++) {
            const float* mrow = Mg + (size_t)(16 * wv + 4 * lg + r) * S_LEN + key0;
#pragma unroll
            for (int nt = 0; nt < 4; nt++) mreg[r][nt] = mrow[16 * nt + lr];
        }
        f32x4 acc[4] = {};
        qkt(Qs, Ks, wv, lr, lg, acc);
#pragma unroll
        for (int r = 0; r < 4; r++) {
            const int row = 16 * wv + 4 * lg + r;
            float* arow = attng + (size_t)row * S_LEN + key0;
#pragma unroll
            for (int nt = 0; nt < 4; nt++) {
                float e = __expf(acc[nt][r] * 0.125f) * mreg[r][nt] * inv[r];
                __builtin_nontemporal_store(e, arow + 16 * nt + lr);
            }
        }
        ldsbar();
    }
}

extern "C" void kernel_launch(void* const* d_in, const int* in_sizes, int n_in,
                              void* d_out, int out_size, void* d_ws, size_t ws_size,
                              hipStream_t stream) {
    const float* Q = (const float*)d_in[0];
    const float* K = (const float*)d_in[1];
    const float* V = (const float*)d_in[2];
    const float* M = (const float*)d_in[3];
    float* out = (float*)d_out;
    unsigned char* wsb = (unsigned char*)d_ws;
    float* invg = (float*)wsb;                         // 512 KB
    unsigned char* wsK = wsb + 512 * 1024;             // 16.8 MB
    unsigned char* wsV = wsK + (size_t)NBH * 32 * 8192;
    const size_t need = 512 * 1024 + 2 * (size_t)NBH * 32 * 8192;   // ~34 MB

    if (ws_size >= need) {
        conv_kv<<<dim3(NBH * 32), dim3(256), 0, stream>>>(K, V, wsK, wsV);
        attn_ctx_pre<<<dim3(NBH * 32), dim3(256), 0, stream>>>(Q, wsK, wsV, M, out, invg);
        attn_mat_pre<<<dim3(NBH * 32 * KSEG), dim3(256), 0, stream>>>(Q, wsK, M, invg, out);
    } else {
        attn_ctx_v11<<<dim3(NBH * 32), dim3(256), 0, stream>>>(Q, K, V, M, out, invg);
        attn_mat_v11<<<dim3(NBH * 32 * KSEG), dim3(256), 0, stream>>>(Q, K, M, invg, out);
    }
}

// Round 18
// 493.567 us; speedup vs baseline: 1.1088x; 1.1088x over previous
//
// v17: k1 = swapped-QKT (mfma(K,Q)), P kept in registers, permlane/shfl
//      redistribution to PV B-frag; no P LDS; 16KB LDS; 2 barriers/tile.
//      k2 = v6 verbatim. Derivation probes: lane0/kh0/j5 and lane40/kh1/j2 OK.
#include <hip/hip_runtime.h>

#define S_LEN 2048
#define D_KD  64
#define NKT   32          // S / 64 k-tiles
#define NBH   64          // B*H
#define KSEG  4           // kernel2: key segments per (bh,qt)

typedef __attribute__((ext_vector_type(8))) short short8;   // 8 bf16 (4 VGPRs)
typedef __attribute__((ext_vector_type(4))) float f32x4;    // MFMA C/D
typedef __attribute__((ext_vector_type(4))) unsigned u32x4; // 4 u32 = short8
typedef __attribute__((ext_vector_type(2))) int int2v;

// ---- bf16 round-to-nearest-even from f32 ----
__device__ __forceinline__ unsigned short f2bf(float f) {
    unsigned u = __builtin_bit_cast(unsigned, f);
    return (unsigned short)((u + 0x7fffu + ((u >> 16) & 1u)) >> 16);
}
__device__ __forceinline__ unsigned pack2(float a, float b) {
    return (unsigned)f2bf(a) | ((unsigned)f2bf(b) << 16);
}
__device__ __forceinline__ short8 pack8(float4 a, float4 b) {
    short8 r;
    r[0] = (short)f2bf(a.x); r[1] = (short)f2bf(a.y);
    r[2] = (short)f2bf(a.z); r[3] = (short)f2bf(a.w);
    r[4] = (short)f2bf(b.x); r[5] = (short)f2bf(b.y);
    r[6] = (short)f2bf(b.z); r[7] = (short)f2bf(b.w);
    return r;
}

// Cross-wave LDS-visibility barrier WITHOUT vmcnt drain.
__device__ __forceinline__ void ldsbar() {
    asm volatile("s_waitcnt lgkmcnt(0)" ::: "memory");
    __builtin_amdgcn_s_barrier();
}

// ---- half-swap: newA = [E0.lo32 | E1.lo32], newB = [E0.hi32 | E1.hi32]
__device__ __forceinline__ void swap32(unsigned e0, unsigned e1,
                                       unsigned& a, unsigned& b, int lane) {
#if __has_builtin(__builtin_amdgcn_permlane32_swap)
    int2v r = __builtin_amdgcn_permlane32_swap((int)e0, (int)e1, false, false);
    a = (unsigned)r[0];   // vdst_new = [e0(0:31) | e1(0:31)]
    b = (unsigned)r[1];   // vsrc_new = [e0(32:63) | e1(32:63)]
#else
    unsigned t0 = __shfl_xor(e0, 32), t1 = __shfl_xor(e1, 32);
    const bool hi = lane >= 32;
    a = hi ? t1 : e0;
    b = hi ? e1 : t0;
#endif
}
// ---- 16-group spread: from X=[G0,G1,G2,G3]: p=[G0,G0,G2,G2], q=[G1,G1,G3,G3]
__device__ __forceinline__ void swap16(unsigned x, unsigned& p, unsigned& q,
                                       int lane) {
#if __has_builtin(__builtin_amdgcn_permlane16_swap)
    int2v r = __builtin_amdgcn_permlane16_swap((int)x, (int)x, false, false);
    p = (unsigned)r[0];
    q = (unsigned)r[1];
#else
    unsigned t = __shfl_xor(x, 16);
    const bool odd = (lane >> 4) & 1;
    p = odd ? t : x;
    q = odd ? x : t;
#endif
}

// ---- XOR swizzle for [64][64] bf16 tiles (row stride 128B).
__device__ __forceinline__ unsigned swz(int row, int bytecol) {
    return (unsigned)(row * 128 + bytecol) ^
           (((((unsigned)row & 7u) ^ ((unsigned)row >> 3)) & 7u) << 4);
}

// ---- register-staged tile load/write (256-thread) ----
__device__ __forceinline__ void load_rm(const float* __restrict__ g,
                                        float4 r[4], int tid) {
#pragma unroll
    for (int j = 0; j < 4; j++) r[j] = *(const float4*)(g + j * 1024 + tid * 4);
}
__device__ __forceinline__ void write_rm(const float4 r[4],
                                         unsigned char* lds, int tid) {
#pragma unroll
    for (int j = 0; j < 4; j++) {
        int idx = j * 1024 + tid * 4;
        int row = idx >> 6, col = idx & 63;
        ushort4 b = make_ushort4(f2bf(r[j].x), f2bf(r[j].y), f2bf(r[j].z), f2bf(r[j].w));
        *(ushort4*)(lds + swz(row, col * 2)) = b;
    }
}
__device__ __forceinline__ void load_tr(const float* __restrict__ g,
                                        float4 r[4], int tid) {
    const int br = tid >> 4, bc = tid & 15;
    const float* gp = g + (4 * br) * 64 + 4 * bc;
#pragma unroll
    for (int j = 0; j < 4; j++) r[j] = *(const float4*)(gp + j * 64);
}
__device__ __forceinline__ void write_tr(const float4 r[4],
                                         unsigned char* lds, int tid) {
    const int br = tid >> 4, bc = tid & 15;
    ushort4 c;
    c = make_ushort4(f2bf(r[0].x), f2bf(r[1].x), f2bf(r[2].x), f2bf(r[3].x));
    *(ushort4*)(lds + swz(4 * bc + 0, 8 * br)) = c;
    c = make_ushort4(f2bf(r[0].y), f2bf(r[1].y), f2bf(r[2].y), f2bf(r[3].y));
    *(ushort4*)(lds + swz(4 * bc + 1, 8 * br)) = c;
    c = make_ushort4(f2bf(r[0].z), f2bf(r[1].z), f2bf(r[2].z), f2bf(r[3].z));
    *(ushort4*)(lds + swz(4 * bc + 2, 8 * br)) = c;
    c = make_ushort4(f2bf(r[0].w), f2bf(r[1].w), f2bf(r[2].w), f2bf(r[3].w));
    *(ushort4*)(lds + swz(4 * bc + 3, 8 * br)) = c;
}
__device__ __forceinline__ void stage_rm(const float* __restrict__ g,
                                         unsigned char* lds, int tid) {
    float4 r[4];
    load_rm(g, r, tid);
    write_rm(r, lds, tid);
}

// 64x64 QK^T, Q from LDS (kernel 2 only).
__device__ __forceinline__ void qkt(const unsigned char* Qs, const unsigned char* Ks,
                                    int wv, int lr, int lg, f32x4 acc[4]) {
    short8 a0 = *(const short8*)(Qs + swz(16 * wv + lr, 16 * lg));
    short8 a1 = *(const short8*)(Qs + swz(16 * wv + lr, 16 * lg + 64));
#pragma unroll
    for (int nt = 0; nt < 4; nt++) {
        short8 b0 = *(const short8*)(Ks + swz(16 * nt + lr, 16 * lg));
        short8 b1 = *(const short8*)(Ks + swz(16 * nt + lr, 16 * lg + 64));
        acc[nt] = __builtin_amdgcn_mfma_f32_16x16x32_bf16(a0, b0, acc[nt], 0, 0, 0);
        acc[nt] = __builtin_amdgcn_mfma_f32_16x16x32_bf16(a1, b1, acc[nt], 0, 0, 0);
    }
}

// ---------------- kernel 1: swapped-QKT, register-P ----------------
__global__ __launch_bounds__(256, 4) void attn_ctx(
    const float* __restrict__ Q, const float* __restrict__ K,
    const float* __restrict__ V, const float* __restrict__ M,
    float* __restrict__ out, float* __restrict__ invg) {
    __shared__ unsigned char Ks[8192];
    __shared__ unsigned char Vs[8192];   // transposed: [dcol][key]

    const int tid = threadIdx.x;
    const int wv = tid >> 6, lane = tid & 63, lr = lane & 15, lg = lane >> 4;
    // v11 XCD-aware remap
    const int blk = blockIdx.x;
    const int bh = (blk & 7) * 8 + (blk >> 8);
    const int qt = (blk >> 3) & 31;

    const float* Kg = K + (size_t)bh * S_LEN * D_KD;
    const float* Vg = V + (size_t)bh * S_LEN * D_KD;
    float* ctxg = out + ((size_t)bh * S_LEN + qt * 64) * D_KD;
    const float* Mg = M + (size_t)(qt * 64) * S_LEN;

    // Q B-fragment in registers (per-lane row = 16wv+lr; layout = A-frag layout)
    short8 qa0, qa1;
    {
        const float* qr = Q + ((size_t)bh * S_LEN + qt * 64 + 16 * wv + lr) * D_KD + 8 * lg;
        qa0 = pack8(*(const float4*)(qr), *(const float4*)(qr + 4));
        qa1 = pack8(*(const float4*)(qr + 32), *(const float4*)(qr + 36));
    }

    f32x4 acc_ctx[4] = {};     // acc_ctx[dt][r] = ctx^T[d=16dt+4lg+r][q=lr]
    float rs = 0.f;            // rowsum partial for q=lr (keys 16nt+4lg+r)

    float4 kreg[4], vreg[4];
    load_rm(Kg, kreg, tid);
    load_tr(Vg, vreg, tid);

    for (int t = 0; t < NKT; t++) {
        write_rm(kreg, Ks, tid);
        write_tr(vreg, Vs, tid);
        ldsbar();                             // staging visible; vm stays in flight

        if (t + 1 < NKT) {
            load_rm(Kg + (size_t)(t + 1) * 64 * D_KD, kreg, tid);
            load_tr(Vg + (size_t)(t + 1) * 64 * D_KD, vreg, tid);
        }

        // mask: per lane row 16wv+lr, cols 16nt+4lg+[0..3] (float4 x4)
        float4 m4[4];
        const float* mbase = Mg + (size_t)(16 * wv + lr) * S_LEN + t * 64 + 4 * lg;
#pragma unroll
        for (int nt = 0; nt < 4; nt++) m4[nt] = *(const float4*)(mbase + 16 * nt);

        // swapped QK^T: sc[nt][r] = S[key=16nt+4lg+r][q=lr]
        f32x4 sc[4] = {};
#pragma unroll
        for (int nt = 0; nt < 4; nt++) {
            short8 kb0 = *(const short8*)(Ks + swz(16 * nt + lr, 16 * lg));
            short8 kb1 = *(const short8*)(Ks + swz(16 * nt + lr, 16 * lg + 64));
            sc[nt] = __builtin_amdgcn_mfma_f32_16x16x32_bf16(kb0, qa0, sc[nt], 0, 0, 0);
            sc[nt] = __builtin_amdgcn_mfma_f32_16x16x32_bf16(kb1, qa1, sc[nt], 0, 0, 0);
        }

        // exp * mask, rowsum, bf16 packs
        float e[4][4];
        unsigned E[4][2];
#pragma unroll
        for (int nt = 0; nt < 4; nt++) {
#pragma unroll
            for (int r = 0; r < 4; r++) {
                float v = __expf(sc[nt][r] * 0.125f) *
                          ((const float*)&m4[nt])[r];
                e[nt][r] = v;
                rs += v;
            }
            E[nt][0] = pack2(e[nt][0], e[nt][1]);
            E[nt][1] = pack2(e[nt][2], e[nt][3]);
        }

        // redistribute to PV B-frag: pb[kh] elem j = P[key=32kh+8lg+j][q=lr]
        short8 pb[2];
#pragma unroll
        for (int kh = 0; kh < 2; kh++) {
            unsigned w[4];
#pragma unroll
            for (int c = 0; c < 2; c++) {
                unsigned nA, nB, pA, qA, pB, qB;
                swap32(E[2 * kh][c], E[2 * kh + 1][c], nA, nB, lane);
                swap16(nA, pA, qA, lane);
                swap16(nB, pB, qB, lane);
                const bool lodd = (lg & 1);
                w[c] = lodd ? pB : pA;
                w[2 + c] = lodd ? qB : qA;
            }
            u32x4 t4 = {w[0], w[1], w[2], w[3]};
            pb[kh] = __builtin_bit_cast(short8, t4);
        }

        // PV: ctx^T += V^T . P^T   (V-frag reads identical to before)
#pragma unroll
        for (int dt = 0; dt < 4; dt++) {
            short8 v0 = *(const short8*)(Vs + swz(16 * dt + lr, 16 * lg));
            short8 v1 = *(const short8*)(Vs + swz(16 * dt + lr, 16 * lg + 64));
            acc_ctx[dt] = __builtin_amdgcn_mfma_f32_16x16x32_bf16(v0, pb[0], acc_ctx[dt], 0, 0, 0);
            acc_ctx[dt] = __builtin_amdgcn_mfma_f32_16x16x32_bf16(v1, pb[1], acc_ctx[dt], 0, 0, 0);
        }
        ldsbar();                             // Ks/Vs reads done before next stage
    }

    // rowsum reduce over lg groups (keys split across lg and nt handled in rs)
    float v = rs;
    v += __shfl_xor(v, 16);
    v += __shfl_xor(v, 32);
    const float inv = 1.0f / (v + 1e-8f);

    // ctx write: row q=16wv+lr, cols 16dt+4lg..+3 (float4)
#pragma unroll
    for (int dt = 0; dt < 4; dt++) {
        float4 o = make_float4(acc_ctx[dt][0] * inv, acc_ctx[dt][1] * inv,
                               acc_ctx[dt][2] * inv, acc_ctx[dt][3] * inv);
        *(float4*)(ctxg + (size_t)(16 * wv + lr) * D_KD + 16 * dt + 4 * lg) = o;
    }
    if (lg == 0)
        invg[(size_t)bh * S_LEN + qt * 64 + 16 * wv + lr] = inv;
}

// ---------------- kernel 2: stream normalized attn (v6 verbatim) ----------------
__global__ __launch_bounds__(256) void attn_mat(
    const float* __restrict__ Q, const float* __restrict__ K,
    const float* __restrict__ M, const float* __restrict__ invg,
    float* __restrict__ out) {
    __shared__ unsigned char Qs[8192];
    __shared__ unsigned char Ks[8192];

    const int tid = threadIdx.x;
    const int wv = tid >> 6, lane = tid & 63, lr = lane & 15, lg = lane >> 4;
    const int ks = blockIdx.x & (KSEG - 1);
    const int qt = (blockIdx.x >> 2) & 31;
    const int bh = blockIdx.x >> 7;

    const float* Qg = Q + ((size_t)bh * S_LEN + qt * 64) * D_KD;
    const float* Kg = K + (size_t)bh * S_LEN * D_KD;
    const float* Mg = M + (size_t)(qt * 64) * S_LEN;
    float* attng = out + (size_t)NBH * S_LEN * D_KD +
                   (size_t)bh * S_LEN * S_LEN + (size_t)(qt * 64) * S_LEN;

    stage_rm(Qg, Qs, tid);

    float inv[4];
#pragma unroll
    for (int r = 0; r < 4; r++)
        inv[r] = invg[(size_t)bh * S_LEN + qt * 64 + 16 * wv + 4 * lg + r];

    const int nt_kt = S_LEN / (64 * KSEG);   // 8 k-tiles per block
    const float* Kseg = Kg + (size_t)(ks * (S_LEN / KSEG)) * D_KD;

    float4 kreg[4];
    load_rm(Kseg, kreg, tid);                // prologue prefetch

    for (int kt = 0; kt < nt_kt; kt++) {
        const int key0 = ks * (S_LEN / KSEG) + kt * 64;
        write_rm(kreg, Ks, tid);             // consume prefetch
        ldsbar();                            // staging visible; stores keep flying

        if (kt + 1 < nt_kt)
            load_rm(Kseg + (size_t)(kt + 1) * 64 * D_KD, kreg, tid);

        float mreg[4][4];
#pragma unroll
        for (int r = 0; r < 4; r++) {
            const float* mrow = Mg + (size_t)(16 * wv + 4 * lg + r) * S_LEN + key0;
#pragma unroll
            for (int nt = 0; nt < 4; nt++) mreg[r][nt] = mrow[16 * nt + lr];
        }

        f32x4 acc[4] = {};
        qkt(Qs, Ks, wv, lr, lg, acc);

#pragma unroll
        for (int r = 0; r < 4; r++) {
            const int row = 16 * wv + 4 * lg + r;
            float* arow = attng + (size_t)row * S_LEN + key0;
#pragma unroll
            for (int nt = 0; nt < 4; nt++) {
                float e = __expf(acc[nt][r] * 0.125f) * mreg[r][nt] * inv[r];
                __builtin_nontemporal_store(e, arow + 16 * nt + lr);
            }
        }
        ldsbar();                            // qkt ds_reads done before overwrite
    }
}

extern "C" void kernel_launch(void* const* d_in, const int* in_sizes, int n_in,
                              void* d_out, int out_size, void* d_ws, size_t ws_size,
                              hipStream_t stream) {
    const float* Q = (const float*)d_in[0];
    const float* K = (const float*)d_in[1];
    const float* V = (const float*)d_in[2];
    const float* M = (const float*)d_in[3];
    float* out = (float*)d_out;
    float* invg = (float*)d_ws;          // 64*2048 floats = 512 KB
    attn_ctx<<<dim3(NBH * 32), dim3(256), 0, stream>>>(Q, K, V, M, out, invg);
    attn_mat<<<dim3(NBH * 32 * KSEG), dim3(256), 0, stream>>>(Q, K, M, invg, out);
}